// Round 6
// baseline (79.937 us; speedup 1.0000x reference)
//
#include <hip/hip_runtime.h>

typedef unsigned short u16;
typedef unsigned int u32;
typedef __bf16 bf16x8 __attribute__((ext_vector_type(8)));
typedef float f32x4 __attribute__((ext_vector_type(4)));

#define B_ 8
#define C_ 64
#define H_ 112
#define W_ 112
#define HW_ 12544
#define F_ 128
#define OH_ 110
#define OW_ 110
#define NPOS 96800
#define KK_ 576
#define NWG 757           // ceil(NPOS/128)
#define OCTSTRIDE 802816  // B_*W_*H_*8 u16 elems per c-oct plane

__device__ __forceinline__ u16 f2bf(float f) {
  u32 u = __builtin_bit_cast(u32, f);
  u32 r = (u + 0x7fffu + ((u >> 16) & 1u)) >> 16;
  return (u16)r;
}
__device__ __forceinline__ float bf2f(u16 h) {
  u32 u = ((u32)h) << 16;
  return __builtin_bit_cast(float, u);
}

__device__ __forceinline__ void gl_lds16(const void* g, void* l) {
  __builtin_amdgcn_global_load_lds((const __attribute__((address_space(1))) void*)g,
                                   (__attribute__((address_space(3))) void*)l,
                                   16, 0, 0);
}

// ---- prep: NCHW fp32 -> [c_oct][b][w][h]{8c} bf16 hi/lo (gl_lds-stageable layout) ----
__global__ __launch_bounds__(256) void prep_inputT(const float* __restrict__ in,
                                                   u16* __restrict__ xTH,
                                                   u16* __restrict__ xTL) {
  __shared__ float tile[8][8][113];  // [c][h][w], w-pad 1
  const int bid = blockIdx.x;        // 8 b x 8 oct x 14 h-stripes = 896
  const int b = bid / 112;
  const int r = bid % 112;
  const int oct = r / 14;
  const int hs = (r % 14) * 8;
  const int tid = threadIdx.x;

  for (int idx = tid; idx < 8 * 8 * 112; idx += 256) {
    int c = idx / 896;
    int rem = idx - c * 896;
    int h = rem / 112;
    int w = rem - h * 112;
    tile[c][h][w] = in[(((size_t)(b * 64 + oct * 8 + c)) * 112 + (hs + h)) * 112 + w];
  }
  __syncthreads();

  for (int idx = tid; idx < 896; idx += 256) {
    int w = idx >> 3;
    int h = idx & 7;
    u32 hw[4], lw[4];
#pragma unroll
    for (int c2 = 0; c2 < 4; ++c2) {
      float v0 = tile[c2 * 2][h][w], v1 = tile[c2 * 2 + 1][h][w];
      u16 h0 = f2bf(v0), h1 = f2bf(v1);
      u16 l0 = f2bf(v0 - bf2f(h0)), l1 = f2bf(v1 - bf2f(h1));
      hw[c2] = (u32)h0 | ((u32)h1 << 16);
      lw[c2] = (u32)l0 | ((u32)l1 << 16);
    }
    size_t o = ((((size_t)oct * B_ + b) * W_ + w) * H_ + (hs + h)) * 8;
    uint4 hv = {hw[0], hw[1], hw[2], hw[3]};
    uint4 lv = {lw[0], lw[1], lw[2], lw[3]};
    *(uint4*)(xTH + o) = hv;
    *(uint4*)(xTL + o) = lv;
  }
}

// ---- prep: kernel fp32 [f][KK] -> fragment-order A'[ko][f][8c] bf16 hi/lo ----
// Conv A-read: quarter-wave = 16 consecutive f at one ko -> 256B contiguous L2 hits.
__global__ __launch_bounds__(256) void prep_kerT(const float* __restrict__ k,
                                                 u16* __restrict__ kTH,
                                                 u16* __restrict__ kTL) {
  int idx = blockIdx.x * 256 + threadIdx.x;
  if (idx < F_ * KK_) {
    int ko = idx >> 10;          // /(128*8)
    int rem = idx & 1023;
    int f = rem >> 3;
    int c = rem & 7;
    float v = k[f * KK_ + ko * 8 + c];
    u16 h = f2bf(v);
    kTH[idx] = h;
    kTL[idx] = f2bf(v - bf2f(h));
  }
}

// ---------------- main: B via gl_lds (2x16KB dbuf), A direct from L2-resident weights ----
// B (25MB, L2-thrash-prone) is fire-and-forget DMA: miss latency absorbed at the barrier,
// never on a reg dependency path (r5's failure mode). A (294KB) is always L2-hit.
// A-globals issued BEFORE next-B gl_lds so consuming A waits vmcnt(4), not vmcnt(0).
// B rows 64B: conflict-free involution chunk ^= (row>>1)&3 (0 conflicts, r3/r4/r5).
__global__ __launch_bounds__(256, 3) void conv_mfma(
    const u16* __restrict__ xTH, const u16* __restrict__ xTL,
    const u16* __restrict__ kTH, const u16* __restrict__ kTL,
    float* __restrict__ out) {
  __shared__ u16 lds[2][2][128 * 32];  // [dbuf][H,L][row][32k]  row stride 64B

  const int tid = threadIdx.x;
  const int wave = tid >> 6;
  const int lane = tid & 63;

  // bijective XCD-aware block swizzle (m204 form; NWG=757: q=94, r=5)
  const int orig = blockIdx.x;
  const int xcd = orig & 7;
  const int sub = orig >> 3;
  const int wg = (xcd < 5 ? xcd * 95 : 475 + (xcd - 5) * 94) + sub;
  const int n0 = wg * 128;

  const int l15 = lane & 15;
  const int l4 = lane >> 4;
  const int wr = wave >> 1;
  const int wc = wave & 1;

  // ---- B staging geometry: per instr a wave covers 16 rows x 64B.
  // lane -> row=lane>>2, dst chunk=lane&3; LDS dest linear, SOURCE chunk pre-swizzled
  // with the read involution: q = (lane&3) ^ ((lane>>3)&3).
  const int rlo = lane >> 2;
  const int q = (lane & 3) ^ ((lane >> 3) & 3);
  int posStage[2];
#pragma unroll
  for (int it = 0; it < 2; ++it) {
    int row = (it * 4 + wave) * 16 + rlo;
    int n = n0 + row;
    if (n >= NPOS) n = 0;
    int b = n / (OW_ * OH_);
    int r = n - b * (OW_ * OH_);
    int w = r / OH_;
    int h = r - w * OH_;
    posStage[it] = ((b * W_ + w) * H_ + h) * 8;
  }

  f32x4 acc[4][4] = {};

  auto stageB = [&](int s, int d) {
    const int tap = s >> 1;
    const int half = s & 1;
    const int i = tap / 3;      // W offset
    const int j = tap - i * 3;  // H offset
    const int shift = (i * H_ + j) * 8;
    const u16* srcH = xTH + (half * 4 + q) * OCTSTRIDE + shift;
    const u16* srcL = xTL + (half * 4 + q) * OCTSTRIDE + shift;
#pragma unroll
    for (int it = 0; it < 2; ++it) {
      const u32 dst = (u32)((it * 4 + wave) * 1024);
      gl_lds16(srcH + posStage[it], (char*)&lds[d][0][0] + dst);
      gl_lds16(srcL + posStage[it], (char*)&lds[d][1][0] + dst);
    }
  };

  stageB(0, 0);
  __syncthreads();

  for (int s = 0; s < 18; ++s) {
    const int cur = s & 1;

    // A: 8 per-lane 16B loads from L2-resident fragment-order weights (issued FIRST)
    bf16x8 ah[4], al[4];
    const int aBase = ((s * 4 + l4) * 128 + wr * 64 + l15) * 8;
#pragma unroll
    for (int mi = 0; mi < 4; ++mi) {
      ah[mi] = *(const bf16x8*)(kTH + aBase + mi * 128);
      al[mi] = *(const bf16x8*)(kTL + aBase + mi * 128);
    }

    if (s < 17) stageB(s + 1, cur ^ 1);  // fire-and-forget; drained at barrier

    // B: 8 ds_read_b128 from current buffer
    bf16x8 bh[4], bl[4];
#pragma unroll
    for (int ni = 0; ni < 4; ++ni) {
      int row = wc * 64 + ni * 16 + l15;
      int e = row * 32 + ((l4 ^ ((row >> 1) & 3)) * 8);
      bh[ni] = *(const bf16x8*)&lds[cur][0][e];
      bl[ni] = *(const bf16x8*)&lds[cur][1][e];
    }

#pragma unroll
    for (int mi = 0; mi < 4; ++mi)
#pragma unroll
      for (int ni = 0; ni < 4; ++ni) {
        acc[mi][ni] = __builtin_amdgcn_mfma_f32_16x16x32_bf16(ah[mi], bh[ni], acc[mi][ni], 0, 0, 0);
        acc[mi][ni] = __builtin_amdgcn_mfma_f32_16x16x32_bf16(ah[mi], bl[ni], acc[mi][ni], 0, 0, 0);
        acc[mi][ni] = __builtin_amdgcn_mfma_f32_16x16x32_bf16(al[mi], bh[ni], acc[mi][ni], 0, 0, 0);
      }

    __syncthreads();  // drains vmcnt (B prefetch) ; WAR for buffer swap
  }

  // epilogue: D col = lane&15 -> n, row = (lane>>4)*4+q -> f
#pragma unroll
  for (int ni = 0; ni < 4; ++ni) {
    int n = n0 + wc * 64 + ni * 16 + l15;
    if (n >= NPOS) continue;
    int b = n / (OW_ * OH_);
    int r = n - b * (OW_ * OH_);
    int w = r / OH_;
    int h = r - w * OH_;
    float* op = out + ((size_t)(b * F_) * OW_ + w) * OH_ + h;
#pragma unroll
    for (int mi = 0; mi < 4; ++mi) {
      int fbase = wr * 64 + mi * 16 + l4 * 4;
#pragma unroll
      for (int qq = 0; qq < 4; ++qq) {
        op[(size_t)(fbase + qq) * (OW_ * OH_)] = acc[mi][ni][qq];
      }
    }
  }
}

// ---------------- correctness fallback (ws too small) ----------------
__global__ void naive_conv(const float* __restrict__ in, const float* __restrict__ ker,
                           float* __restrict__ out) {
  int idx = blockIdx.x * 256 + threadIdx.x;
  const int total = B_ * F_ * OW_ * OH_;
  if (idx >= total) return;
  int h = idx % OH_;
  int w = (idx / OH_) % OW_;
  int f = (idx / (OW_ * OH_)) % F_;
  int b = idx / (F_ * OW_ * OH_);
  float s = 0.f;
  for (int tap = 0; tap < 9; ++tap) {
    int i = tap / 3, j = tap % 3;
    const float* ip = in + ((size_t)b * C_ * H_ + (h + j)) * W_ + (w + i);
    const float* kp = ker + (size_t)f * KK_ + tap * C_;
    for (int c = 0; c < C_; ++c) s += ip[(size_t)c * HW_] * kp[c];
  }
  out[idx] = s;
}

extern "C" void kernel_launch(void* const* d_in, const int* in_sizes, int n_in,
                              void* d_out, int out_size, void* d_ws, size_t ws_size,
                              hipStream_t stream) {
  const float* in = (const float*)d_in[0];
  const float* ker = (const float*)d_in[1];
  float* out = (float*)d_out;

  const size_t xElems = (size_t)B_ * H_ * W_ * C_;  // 6,422,528
  const size_t kElems = (size_t)F_ * KK_;           // 73,728
  const size_t need = xElems * 2 * 2 + kElems * 2 * 2;

  if (ws_size < need) {
    int total = B_ * F_ * OW_ * OH_;
    naive_conv<<<(total + 255) / 256, 256, 0, stream>>>(in, ker, out);
    return;
  }

  u16* xTH = (u16*)d_ws;
  u16* xTL = xTH + xElems;
  u16* kTH = xTL + xElems;
  u16* kTL = kTH + kElems;

  prep_inputT<<<896, 256, 0, stream>>>(in, xTH, xTL);
  prep_kerT<<<(int)((kElems + 255) / 256), 256, 0, stream>>>(ker, kTH, kTL);
  conv_mfma<<<NWG, 256, 0, stream>>>(xTH, xTL, kTH, kTL, out);
}

// Round 7
// 43.682 us; speedup vs baseline: 1.8300x; 1.8300x over previous
//
#include <hip/hip_runtime.h>

typedef unsigned short u16;
typedef unsigned int u32;
typedef _Float16 f16x8 __attribute__((ext_vector_type(8)));
typedef float f32x4 __attribute__((ext_vector_type(4)));

#define B_ 8
#define C_ 64
#define H_ 112
#define W_ 112
#define HW_ 12544
#define F_ 128
#define OH_ 110
#define OW_ 110
#define NPOS 96800
#define KK_ 576
#define NWG 757           // ceil(NPOS/128)
#define OCTSTRIDE 802816  // B_*W_*H_*8 elems per c-oct plane

__device__ __forceinline__ void gl_lds16(const void* g, void* l) {
  __builtin_amdgcn_global_load_lds((const __attribute__((address_space(1))) void*)g,
                                   (__attribute__((address_space(3))) void*)l,
                                   16, 0, 0);
}

// ---- prep: NCHW fp32 -> [c_oct][b][w][h]{8c} fp16 (B direct-load layout) ----
__global__ __launch_bounds__(256) void prep_inputT(const float* __restrict__ in,
                                                   u16* __restrict__ xT) {
  __shared__ float tile[8][8][113];  // [c][h][w], w-pad 1
  const int bid = blockIdx.x;        // 8 b x 8 oct x 14 h-stripes = 896
  const int b = bid / 112;
  const int r = bid % 112;
  const int oct = r / 14;
  const int hs = (r % 14) * 8;
  const int tid = threadIdx.x;

  for (int idx = tid; idx < 8 * 8 * 112; idx += 256) {
    int c = idx / 896;
    int rem = idx - c * 896;
    int h = rem / 112;
    int w = rem - h * 112;
    tile[c][h][w] = in[(((size_t)(b * 64 + oct * 8 + c)) * 112 + (hs + h)) * 112 + w];
  }
  __syncthreads();

  for (int idx = tid; idx < 896; idx += 256) {
    int w = idx >> 3;
    int h = idx & 7;
    f16x8 v;
#pragma unroll
    for (int c = 0; c < 8; ++c) v[c] = (_Float16)tile[c][h][w];
    size_t o = ((((size_t)oct * B_ + b) * W_ + w) * H_ + (hs + h)) * 8;
    *(f16x8*)(xT + o) = v;
  }
}

// ---- prep: kernel fp32 [f][KK] -> fp16 [f][KK] ----
__global__ __launch_bounds__(256) void prep_ker(const float* __restrict__ k,
                                                u16* __restrict__ kT) {
  int idx = blockIdx.x * 256 + threadIdx.x;
  if (idx < F_ * KK_) {
    _Float16 h = (_Float16)k[idx];
    kT[idx] = __builtin_bit_cast(u16, h);
  }
}

// ---------------- main: fp16 single-term; A via gl_lds dbuf (2x8KB), B direct ----
// r5 structure (best measured) fp16-ified. Issue order per step: B direct loads FIRST,
// then next-step A gl_lds -> MFMA's B-wait is vmcnt(2), A-prefetch flies to the barrier
// (r5 had stage-first, forcing vmcnt(0) at B-consume).
// A rows 64B (16 banks): conflict-free involution oct ^= (row>>1)&3 (0 conflicts r3-r6).
__global__ __launch_bounds__(256, 4) void conv_mfma(
    const u16* __restrict__ xT, const u16* __restrict__ kT,
    float* __restrict__ out) {
  __shared__ u16 lds[2][128 * 32];  // [dbuf][row][32k] fp16, row stride 64B

  const int tid = threadIdx.x;
  const int wave = tid >> 6;
  const int lane = tid & 63;

  // bijective XCD-aware block swizzle (m204 form; NWG=757: q=94, r=5)
  const int orig = blockIdx.x;
  const int xcd = orig & 7;
  const int sub = orig >> 3;
  const int wg = (xcd < 5 ? xcd * 95 : 475 + (xcd - 5) * 94) + sub;
  const int n0 = wg * 128;

  const int l15 = lane & 15;
  const int l4 = lane >> 4;
  const int wr = wave >> 1;
  const int wc = wave & 1;

  // ---- A staging geometry: per instr a wave covers 16 rows x 64B; lane->row=lane>>2,
  // dst chunk=lane&3; LDS dest linear, SOURCE chunk pre-swizzled with read involution:
  // q = (lane&3) ^ ((lane>>3)&3).
  const int rlo = lane >> 2;
  const int q = (lane & 3) ^ ((lane >> 3) & 3);
  int aOff[2];
#pragma unroll
  for (int it = 0; it < 2; ++it) {
    int row = (it * 4 + wave) * 16 + rlo;
    aOff[it] = row * KK_ + q * 8;
  }

  // ---- B addressing: per-lane position offsets (elems), one per ni
  int posOff[4];
#pragma unroll
  for (int ni = 0; ni < 4; ++ni) {
    int n = n0 + wc * 64 + ni * 16 + l15;
    if (n >= NPOS) n = 0;
    int b = n / (OW_ * OH_);
    int r = n - b * (OW_ * OH_);
    int w = r / OH_;
    int h = r - w * OH_;
    posOff[ni] = ((b * W_ + w) * H_ + h) * 8;
  }
  const int l4Off = l4 * OCTSTRIDE;

  f32x4 acc[4][4] = {};

  auto stageA = [&](int s, int d) {
    const int tap = s >> 1;
    const int half = s & 1;
    const int offA = tap * C_ + half * 32;
#pragma unroll
    for (int it = 0; it < 2; ++it) {
      const u32 dst = (u32)((it * 4 + wave) * 1024);
      gl_lds16(kT + aOff[it] + offA, (char*)&lds[d][0] + dst);
    }
  };

  stageA(0, 0);
  __syncthreads();

  for (int s = 0; s < 18; ++s) {
    const int cur = s & 1;
    const int tap = s >> 1;
    const int half = s & 1;
    const int i = tap / 3;      // W offset
    const int j = tap - i * 3;  // H offset
    const int sShift = (i * H_ + j) * 8 + half * 4 * OCTSTRIDE;

    // B: 4 per-lane 16B loads from L2 (issued FIRST)
    f16x8 bh[4];
#pragma unroll
    for (int ni = 0; ni < 4; ++ni) {
      bh[ni] = *(const f16x8*)(xT + posOff[ni] + l4Off + sShift);
    }

    if (s < 17) stageA(s + 1, cur ^ 1);  // in flight until the barrier

    // A: 4 ds_read_b128 from current buffer
    f16x8 ah[4];
#pragma unroll
    for (int mi = 0; mi < 4; ++mi) {
      int row = wr * 64 + mi * 16 + l15;
      int e = row * 32 + ((l4 ^ ((row >> 1) & 3)) * 8);
      ah[mi] = *(const f16x8*)&lds[cur][e];
    }

#pragma unroll
    for (int mi = 0; mi < 4; ++mi)
#pragma unroll
      for (int ni = 0; ni < 4; ++ni) {
        acc[mi][ni] = __builtin_amdgcn_mfma_f32_16x16x32_f16(ah[mi], bh[ni], acc[mi][ni], 0, 0, 0);
      }

    __syncthreads();  // buffer swap; drains A prefetch
  }

  // epilogue: D col = lane&15 -> n, row = (lane>>4)*4+q -> f
#pragma unroll
  for (int ni = 0; ni < 4; ++ni) {
    int n = n0 + wc * 64 + ni * 16 + l15;
    if (n >= NPOS) continue;
    int b = n / (OW_ * OH_);
    int r = n - b * (OW_ * OH_);
    int w = r / OH_;
    int h = r - w * OH_;
    float* op = out + ((size_t)(b * F_) * OW_ + w) * OH_ + h;
#pragma unroll
    for (int mi = 0; mi < 4; ++mi) {
      int fbase = wr * 64 + mi * 16 + l4 * 4;
#pragma unroll
      for (int qq = 0; qq < 4; ++qq) {
        op[(size_t)(fbase + qq) * (OW_ * OH_)] = acc[mi][ni][qq];
      }
    }
  }
}

// ---------------- correctness fallback (ws too small) ----------------
__global__ void naive_conv(const float* __restrict__ in, const float* __restrict__ ker,
                           float* __restrict__ out) {
  int idx = blockIdx.x * 256 + threadIdx.x;
  const int total = B_ * F_ * OW_ * OH_;
  if (idx >= total) return;
  int h = idx % OH_;
  int w = (idx / OH_) % OW_;
  int f = (idx / (OW_ * OH_)) % F_;
  int b = idx / (F_ * OW_ * OH_);
  float s = 0.f;
  for (int tap = 0; tap < 9; ++tap) {
    int i = tap / 3, j = tap % 3;
    const float* ip = in + ((size_t)b * C_ * H_ + (h + j)) * W_ + (w + i);
    const float* kp = ker + (size_t)f * KK_ + tap * C_;
    for (int c = 0; c < C_; ++c) s += ip[(size_t)c * HW_] * kp[c];
  }
  out[idx] = s;
}

extern "C" void kernel_launch(void* const* d_in, const int* in_sizes, int n_in,
                              void* d_out, int out_size, void* d_ws, size_t ws_size,
                              hipStream_t stream) {
  const float* in = (const float*)d_in[0];
  const float* ker = (const float*)d_in[1];
  float* out = (float*)d_out;

  const size_t xElems = (size_t)B_ * H_ * W_ * C_;  // 6,422,528
  const size_t kElems = (size_t)F_ * KK_;           // 73,728
  const size_t need = (xElems + kElems) * 2;        // ~13 MB fp16

  if (ws_size < need) {
    int total = B_ * F_ * OW_ * OH_;
    naive_conv<<<(total + 255) / 256, 256, 0, stream>>>(in, ker, out);
    return;
  }

  u16* xT = (u16*)d_ws;
  u16* kT = xT + xElems;

  prep_inputT<<<896, 256, 0, stream>>>(in, xT);
  prep_ker<<<(int)((kElems + 255) / 256), 256, 0, stream>>>(ker, kT);
  conv_mfma<<<NWG, 256, 0, stream>>>(xT, kT, out);
}